// Round 7
// baseline (346.534 us; speedup 1.0000x reference)
//
#include <hip/hip_runtime.h>

typedef __attribute__((ext_vector_type(8))) short short8;
typedef __attribute__((ext_vector_type(4))) float floatx4;
typedef __attribute__((ext_vector_type(16))) float floatx16;
typedef __attribute__((ext_vector_type(4))) int intx4;

#define NPIX 4096
#define CH 256

static __device__ __forceinline__ unsigned short f2bf(float f) {
  union { float f; unsigned int u; } v; v.f = f;
  unsigned int u = v.u;
  return (unsigned short)((u + 0x7FFFu + ((u >> 16) & 1u)) >> 16);
}

// pack bf16(a) | bf16(b)<<16 : 3 VALU ops
static __device__ __forceinline__ unsigned int pk2bf(float a, float b) {
  union { float f; unsigned int u; } x, y; x.f = a; y.f = b;
  return __builtin_amdgcn_perm(y.u + 0x8000u, x.u + 0x8000u, 0x07060302u);
}

typedef __attribute__((address_space(3))) unsigned int lds_uint;
typedef const __attribute__((address_space(1))) unsigned int glob_uint;
static __device__ __forceinline__ void gload16(const void* g, void* l) {
  __builtin_amdgcn_global_load_lds((glob_uint*)g, (lds_uint*)l, 16, 0, 0);
}

// ---------------- weights fp32 -> bf16 ----------------
__global__ void conv_weights_kernel(const float* __restrict__ wq, const float* __restrict__ wk,
                                    const float* __restrict__ wv, const float* __restrict__ wo,
                                    unsigned short* __restrict__ wqkv, unsigned short* __restrict__ wob) {
  int i = blockIdx.x * 256 + threadIdx.x;   // 0..65535
  wqkv[i]          = f2bf(wq[i]);
  wqkv[65536 + i]  = f2bf(wk[i]);
  wqkv[131072 + i] = f2bf(wv[i]);
  wob[i]           = f2bf(wo[i]);
}

// ---------------- GroupNorm -> xnT bf16 [b][n][c], single HBM pass via LDS slab ------
__global__ __launch_bounds__(256) void gn_kernel(const float* __restrict__ x,
                                                 const float* __restrict__ gsc,
                                                 const float* __restrict__ gbi,
                                                 unsigned short* __restrict__ xnT) {
  __shared__ float xs[8 * 4096];   // 128 KB: the (b,g) channel slab
  __shared__ float red[12];
  int blk = blockIdx.x; int b = blk >> 5; int g = blk & 31;
  int c0 = g * 8;
  const float* xb = x + ((size_t)b * CH + c0) * NPIX;
  int tid = threadIdx.x;
  float s = 0.f, ss = 0.f;
#pragma unroll
  for (int ci = 0; ci < 8; ++ci) {
    const floatx4* p = (const floatx4*)(xb + (size_t)ci * NPIX);
    floatx4* ls = (floatx4*)(xs + ci * 4096);
    for (int n4 = tid; n4 < 1024; n4 += 256) {
      floatx4 v = p[n4];
      ls[n4] = v;
      s += v[0] + v[1] + v[2] + v[3];
      ss += v[0]*v[0] + v[1]*v[1] + v[2]*v[2] + v[3]*v[3];
    }
  }
#pragma unroll
  for (int o = 32; o > 0; o >>= 1) { s += __shfl_down(s, o); ss += __shfl_down(ss, o); }
  int wid = tid >> 6;
  if ((tid & 63) == 0) { red[wid] = s; red[4 + wid] = ss; }
  __syncthreads();
  if (tid == 0) {
    float S = red[0] + red[1] + red[2] + red[3];
    float SS = red[4] + red[5] + red[6] + red[7];
    float mean = S * (1.f / 32768.f);
    float var = SS * (1.f / 32768.f) - mean * mean;
    red[8] = mean; red[9] = rsqrtf(var + 1e-5f);
  }
  __syncthreads();
  float mean = red[8], rstd = red[9];
  float sc[8], bi[8];
#pragma unroll
  for (int ci = 0; ci < 8; ++ci) {
    float scale = gsc[c0 + ci] * rstd;
    sc[ci] = scale;
    bi[ci] = gbi[c0 + ci] - mean * scale;
  }
  for (int n4 = tid; n4 < 1024; n4 += 256) {
    floatx4 v[8];
#pragma unroll
    for (int ci = 0; ci < 8; ++ci) v[ci] = ((const floatx4*)(xs + ci * 4096))[n4];
#pragma unroll
    for (int j = 0; j < 4; ++j) {
      alignas(16) unsigned short tmp[8];
#pragma unroll
      for (int ci = 0; ci < 8; ++ci) tmp[ci] = f2bf(v[ci][j] * sc[ci] + bi[ci]);
      *(intx4*)(xnT + ((size_t)(b * NPIX + n4 * 4 + j)) * CH + c0) = *(const intx4*)tmp;
    }
  }
}

// ---------------- QKV GEMM: D[o,n] = sum_c W[o,c]*xnT[n,c] + bias ----------------
// q pre-scaled by log2e/16 ; q,k written [n][o] bf16 ; v written [o][n] bf16
__global__ __launch_bounds__(256, 2) void qkv_gemm(
    const unsigned short* __restrict__ wqkv, const unsigned short* __restrict__ xnT,
    const float* __restrict__ bq, const float* __restrict__ bk, const float* __restrict__ bv,
    unsigned short* __restrict__ qT, unsigned short* __restrict__ kT, unsigned short* __restrict__ vC) {
  int nt = blockIdx.x, ot = blockIdx.y, bz = blockIdx.z;
  int which = bz % 3, b = bz / 3;
  const unsigned short* W = wqkv + which * 65536;
  const float* bias = which == 0 ? bq : (which == 1 ? bk : bv);
  const unsigned short* X = xnT + (size_t)b * NPIX * CH;
  int o0 = ot * 128, n0 = nt * 128;

  __shared__ unsigned short As[128 * 64];
  __shared__ unsigned short Bs[128 * 64];

  int tid = threadIdx.x;
  int wave = tid >> 6, lane = tid & 63, quad = lane >> 4, l16 = lane & 15;
  int wm = (wave >> 1) * 64, wn = (wave & 1) * 64;

  floatx4 acc[4][4];
#pragma unroll
  for (int i = 0; i < 4; ++i)
#pragma unroll
    for (int j = 0; j < 4; ++j) acc[i][j] = (floatx4){0.f, 0.f, 0.f, 0.f};

  for (int k0 = 0; k0 < 256; k0 += 64) {
    __syncthreads();
#pragma unroll
    for (int c2 = 0; c2 < 4; ++c2) {
      int row = wave * 32 + c2 * 8 + (lane >> 3);
      int sc = (lane & 7) ^ (row & 7);
      gload16(W + (size_t)(o0 + row) * CH + k0 + sc * 8, &As[(wave * 32 + c2 * 8) * 64]);
      gload16(X + (size_t)(n0 + row) * CH + k0 + sc * 8, &Bs[(wave * 32 + c2 * 8) * 64]);
    }
    __syncthreads();
#pragma unroll
    for (int s = 0; s < 2; ++s) {
      short8 af[4], bf[4];
#pragma unroll
      for (int i = 0; i < 4; ++i) {
        int m = wm + i * 16 + l16;
        af[i] = *(const short8*)(As + m * 64 + (((s * 4 + quad) ^ (m & 7)) * 8));
        int n = wn + i * 16 + l16;
        bf[i] = *(const short8*)(Bs + n * 64 + (((s * 4 + quad) ^ (n & 7)) * 8));
      }
#pragma unroll
      for (int i = 0; i < 4; ++i)
#pragma unroll
        for (int j = 0; j < 4; ++j)
          acc[i][j] = __builtin_amdgcn_mfma_f32_16x16x32_bf16(af[i], bf[j], acc[i][j], 0, 0, 0);
    }
  }

  if (which < 2) {
    // 0.0625 * log2(e)
    float qs = (which == 0) ? 0.090168440f : 1.0f;
    unsigned short* outp = (which == 0 ? qT : kT) + (size_t)b * NPIX * CH;
#pragma unroll
    for (int i = 0; i < 4; ++i) {
      int obase = o0 + wm + i * 16 + quad * 4;
      float bias4[4];
#pragma unroll
      for (int r = 0; r < 4; ++r) bias4[r] = bias[obase + r];
#pragma unroll
      for (int j = 0; j < 4; ++j) {
        int n = n0 + wn + j * 16 + l16;
        uint2 pk;
        pk.x = pk2bf((acc[i][j][0] + bias4[0]) * qs, (acc[i][j][1] + bias4[1]) * qs);
        pk.y = pk2bf((acc[i][j][2] + bias4[2]) * qs, (acc[i][j][3] + bias4[3]) * qs);
        *(uint2*)(outp + (size_t)n * CH + obase) = pk;
      }
    }
  } else {
    unsigned short* outp = vC + (size_t)b * CH * NPIX;
#pragma unroll
    for (int i = 0; i < 4; ++i)
#pragma unroll
      for (int r = 0; r < 4; ++r) {
        int o = o0 + wm + i * 16 + quad * 4 + r;
        float bb = bias[o];
#pragma unroll
        for (int j = 0; j < 4; ++j) {
          int n = n0 + wn + j * 16 + l16;
          outp[(size_t)o * NPIX + n] = f2bf(acc[i][j][r] + bb);
        }
      }
  }
}

// ---------------- fused attention: producer-consumer wave specialization ----------------
// grid 256 (1 block/CU): b = bid&7 (XCD-pinned), qt = bid>>3, q-tile 128. KTILE=32,
// 128 m-tiles. Waves 0-3 = S-producers (q-slice w*32): S^T(t) = K(t)·Q^T (32x32x16),
// exp2 (log2e in Q, no max-sub), P(t)->Plds[t&1]. Waves 4-7 = PV-consumers (c-slice
// (w-4)*64): stage K(t+1)/V(t) via global_load_lds, compute O^T += V(t-1)·P(t-1)^T.
// ONE full barrier per iter; all its waits are on work issued a full iter earlier.
// K/V/P all double-buffered; 80.5 KB LDS.
__global__ __launch_bounds__(512, 2) void attn_kernel(
    const unsigned short* __restrict__ qT, const unsigned short* __restrict__ kT,
    const unsigned short* __restrict__ vC, unsigned short* __restrict__ aT) {
  __shared__ unsigned short Klds[2][32 * 256];   // [m][c], chunk-swz m&7
  __shared__ unsigned short Vlds[2][256 * 32];   // [c][m], chunk-swz (c>>1)&3
  __shared__ unsigned short Plds[2][128 * 32];   // [q][m], chunk-swz (q>>1)&3
  __shared__ float lred[128];

  const int tid = threadIdx.x;
  const int w = tid >> 6, lane = tid & 63;
  const int l32 = lane & 31, h = lane >> 5;
  const int b = blockIdx.x & 7, qt = blockIdx.x >> 3;
  const int qbase = qt * 128;

  const unsigned short* Kb = kT + (size_t)b * NPIX * CH;
  const unsigned short* Vb = vC + (size_t)b * CH * NPIX;

#define BARRIER() asm volatile("s_waitcnt vmcnt(0) lgkmcnt(0)\ns_barrier" ::: "memory")

  if (w < 4) {
    // ================= S-producer =================
    const int qsl = w * 32;
    const int q = qsl + l32;
    const int swq = (q >> 1) & 3;
    const int mx = l32 & 7;
    short8 qf[16];
    {
      const unsigned short* qp = qT + ((size_t)(b * NPIX + qbase + q)) * CH + h * 8;
#pragma unroll
      for (int s = 0; s < 16; ++s) qf[s] = *(const short8*)(qp + s * 16);
    }
    float l_acc = 0.f;
    for (int t = 0; t < 129; ++t) {
      BARRIER();
      if (t < 128) {
        const unsigned short* kr = &Klds[t & 1][l32 * 256];
        floatx16 s0 = {}, s1 = {};   // two chains halve MFMA dep latency
#pragma unroll
        for (int s = 0; s < 8; ++s) {
          short8 kf0 = *(const short8*)(kr + (((s * 2 + h) ^ mx) * 8));
          short8 kf1 = *(const short8*)(kr + ((((s + 8) * 2 + h) ^ mx) * 8));
          s0 = __builtin_amdgcn_mfma_f32_32x32x16_bf16(kf0, qf[s], s0, 0, 0, 0);
          s1 = __builtin_amdgcn_mfma_f32_32x32x16_bf16(kf1, qf[s + 8], s1, 0, 0, 0);
        }
        float sum = 0.f;
#pragma unroll
        for (int r = 0; r < 16; ++r) {
          float pv = exp2f(s0[r] + s1[r]);
          s0[r] = pv; sum += pv;
        }
        l_acc += sum;
        unsigned short* Pw = Plds[t & 1];
#pragma unroll
        for (int t4 = 0; t4 < 4; ++t4) {
          int phys = t4 ^ swq;
          uint2 wv;
          wv.x = pk2bf(s0[4 * t4], s0[4 * t4 + 1]);
          wv.y = pk2bf(s0[4 * t4 + 2], s0[4 * t4 + 3]);
          *(uint2*)&Pw[q * 32 + phys * 8 + h * 4] = wv;
        }
      }
    }
    l_acc += __shfl_xor(l_acc, 32);
    if (lane < 32) lred[q] = l_acc;
    BARRIER();   // joins PV tail barrier
  } else {
    // ================= PV-consumer (+ all staging) =================
    const int p = w - 4;
    const int csl = p * 64;
    floatx16 oacc[2][4];
#pragma unroll
    for (int i = 0; i < 2; ++i)
#pragma unroll
      for (int j = 0; j < 4; ++j) oacc[i][j] = (floatx16){0.f};
    // prologue: stage K(0)
#pragma unroll
    for (int j = 0; j < 4; ++j) {
      int r0 = p * 8 + j * 2 + h;
      gload16(Kb + (size_t)r0 * CH + (((lane & 31) ^ (r0 & 7)) * 8),
              &Klds[0][(p * 8 + j * 2) * 256]);
    }
    for (int t = 0; t < 129; ++t) {
      BARRIER();
      if (t < 128) {
        // stage V(t) -> Vlds[t&1]
        const int m0 = t * 32;
#pragma unroll
        for (int j = 0; j < 4; ++j) {
          int r = p * 64 + j * 16 + (lane >> 2);
          gload16(Vb + (size_t)r * NPIX + m0 + (((lane & 3) ^ ((r >> 1) & 3)) * 8),
                  &Vlds[t & 1][(p * 64 + j * 16) * 32]);
        }
        if (t + 1 < 128) {
          const int m1 = (t + 1) * 32;
#pragma unroll
          for (int j = 0; j < 4; ++j) {
            int r0 = p * 8 + j * 2 + h;
            gload16(Kb + (size_t)(m1 + r0) * CH + (((lane & 31) ^ (r0 & 7)) * 8),
                    &Klds[(t + 1) & 1][(p * 8 + j * 2) * 256]);
          }
        }
      }
      if (t >= 1) {
        const int pb = (t - 1) & 1;
#pragma unroll
        for (int mstep = 0; mstep < 2; ++mstep) {
          short8 pf[4], vf[2];
#pragma unroll
          for (int qs = 0; qs < 4; ++qs) {
            int q = qs * 32 + l32;
            pf[qs] = *(const short8*)&Plds[pb][q * 32 + (((mstep * 2 + h) ^ ((q >> 1) & 3)) * 8)];
          }
#pragma unroll
          for (int cs = 0; cs < 2; ++cs) {
            int c = csl + cs * 32 + l32;
            vf[cs] = *(const short8*)&Vlds[pb][c * 32 + (((mstep * 2 + h) ^ ((c >> 1) & 3)) * 8)];
          }
#pragma unroll
          for (int cs = 0; cs < 2; ++cs)
#pragma unroll
            for (int qs = 0; qs < 4; ++qs)
              oacc[cs][qs] =
                  __builtin_amdgcn_mfma_f32_32x32x16_bf16(vf[cs], pf[qs], oacc[cs][qs], 0, 0, 0);
        }
      }
    }
    BARRIER();   // joins S tail barrier; lred now visible
    float iv[4];
#pragma unroll
    for (int qs = 0; qs < 4; ++qs) iv[qs] = 1.f / lred[qs * 32 + l32];
    unsigned short* ab = aT + (size_t)b * NPIX * CH;
#pragma unroll
    for (int cs = 0; cs < 2; ++cs)
#pragma unroll
      for (int qs = 0; qs < 4; ++qs) {
        size_t qg = qbase + qs * 32 + l32;
        float v = iv[qs];
#pragma unroll
        for (int t4 = 0; t4 < 4; ++t4) {
          int c = csl + cs * 32 + 8 * t4 + 4 * h;
          uint2 wv;
          wv.x = pk2bf(oacc[cs][qs][4 * t4] * v, oacc[cs][qs][4 * t4 + 1] * v);
          wv.y = pk2bf(oacc[cs][qs][4 * t4 + 2] * v, oacc[cs][qs][4 * t4 + 3] * v);
          *(uint2*)(ab + qg * CH + c) = wv;
        }
      }
  }
#undef BARRIER
}

// ---------------- output projection + bias + residual ----------------
__global__ __launch_bounds__(256, 2) void out_gemm(
    const unsigned short* __restrict__ wob, const unsigned short* __restrict__ aT,
    const float* __restrict__ bo, const float* __restrict__ x, float* __restrict__ outp) {
  int nt = blockIdx.x, ot = blockIdx.y, b = blockIdx.z;
  const unsigned short* A = aT + (size_t)b * NPIX * CH;
  int o0 = ot * 128, n0 = nt * 128;

  __shared__ unsigned short As[128 * 64];
  __shared__ unsigned short Bs[128 * 64];

  int tid = threadIdx.x;
  int wave = tid >> 6, lane = tid & 63, quad = lane >> 4, l16 = lane & 15;
  int wm = (wave >> 1) * 64, wn = (wave & 1) * 64;

  floatx4 acc[4][4];
#pragma unroll
  for (int i = 0; i < 4; ++i)
#pragma unroll
    for (int j = 0; j < 4; ++j) acc[i][j] = (floatx4){0.f, 0.f, 0.f, 0.f};

  for (int k0 = 0; k0 < 256; k0 += 64) {
    __syncthreads();
#pragma unroll
    for (int c2 = 0; c2 < 4; ++c2) {
      int row = wave * 32 + c2 * 8 + (lane >> 3);
      int sc = (lane & 7) ^ (row & 7);
      gload16(wob + (size_t)(o0 + row) * CH + k0 + sc * 8, &As[(wave * 32 + c2 * 8) * 64]);
      gload16(A + (size_t)(n0 + row) * CH + k0 + sc * 8, &Bs[(wave * 32 + c2 * 8) * 64]);
    }
    __syncthreads();
#pragma unroll
    for (int s = 0; s < 2; ++s) {
      short8 af[4], bf[4];
#pragma unroll
      for (int i = 0; i < 4; ++i) {
        int m = wm + i * 16 + l16;
        af[i] = *(const short8*)(As + m * 64 + (((s * 4 + quad) ^ (m & 7)) * 8));
        int n = wn + i * 16 + l16;
        bf[i] = *(const short8*)(Bs + n * 64 + (((s * 4 + quad) ^ (n & 7)) * 8));
      }
#pragma unroll
      for (int i = 0; i < 4; ++i)
#pragma unroll
        for (int j = 0; j < 4; ++j)
          acc[i][j] = __builtin_amdgcn_mfma_f32_16x16x32_bf16(af[i], bf[j], acc[i][j], 0, 0, 0);
    }
  }

#pragma unroll
  for (int i = 0; i < 4; ++i)
#pragma unroll
    for (int r = 0; r < 4; ++r) {
      int o = o0 + wm + i * 16 + quad * 4 + r;
      float bb = bo[o];
#pragma unroll
      for (int j = 0; j < 4; ++j) {
        int n = n0 + wn + j * 16 + l16;
        size_t idx = ((size_t)b * CH + o) * NPIX + n;
        outp[idx] = x[idx] + bb + acc[i][j][r];
      }
    }
}

extern "C" void kernel_launch(void* const* d_in, const int* in_sizes, int n_in,
                              void* d_out, int out_size, void* d_ws, size_t ws_size,
                              hipStream_t stream) {
  const float* x   = (const float*)d_in[0];
  const float* gsc = (const float*)d_in[1];
  const float* gbi = (const float*)d_in[2];
  const float* wq  = (const float*)d_in[3];
  const float* bq  = (const float*)d_in[4];
  const float* wk  = (const float*)d_in[5];
  const float* bk  = (const float*)d_in[6];
  const float* wv  = (const float*)d_in[7];
  const float* bv  = (const float*)d_in[8];
  const float* wo  = (const float*)d_in[9];
  const float* bo  = (const float*)d_in[10];
  float* out = (float*)d_out;

  char* ws = (char*)d_ws;
  unsigned short* xnT  = (unsigned short*)(ws);              // 16 MB (dead after qkv)
  unsigned short* qT   = (unsigned short*)(ws + 16777216);   // 16 MB
  unsigned short* kT   = (unsigned short*)(ws + 33554432);   // 16 MB
  unsigned short* vC   = (unsigned short*)(ws + 50331648);   // 16 MB
  unsigned short* wqkv = (unsigned short*)(ws + 67108864);   // 384 KB
  unsigned short* wob  = (unsigned short*)(ws + 67502080);   // 128 KB
  unsigned short* aT   = (unsigned short*)(ws + 67633152);   // 16 MB

  conv_weights_kernel<<<256, 256, 0, stream>>>(wq, wk, wv, wo, wqkv, wob);
  gn_kernel<<<256, 256, 0, stream>>>(x, gsc, gbi, xnT);
  dim3 g1(32, 2, 24);
  qkv_gemm<<<g1, 256, 0, stream>>>(wqkv, xnT, bq, bk, bv, qT, kT, vC);
  attn_kernel<<<256, 512, 0, stream>>>(qT, kT, vC, aT);
  dim3 g3(32, 2, 8);
  out_gemm<<<g3, 256, 0, stream>>>(wob, aT, bo, x, out);
}